// Round 2
// baseline (524.284 us; speedup 1.0000x reference)
//
#include <hip/hip_runtime.h>

// Problem constants (fixed by the reference):
constexpr int   T_ = 1000, B_ = 64, C_ = 512, S_ = 100;
constexpr int   L_ = 2 * S_ + 1;     // 201 extended states
constexpr float NEGF = -1e30f;
constexpr int   PF = 16;             // prefetch ring depth (covers ~HBM latency)
constexpr int   ENT_BLOCKS = 1984;   // entropy blocks (total grid = 64 + 1984 = 2048)

__device__ __forceinline__ float lae2(float a, float b) {
  float m = fmaxf(a, b);
  float d = fminf(a, b) - m;           // <= 0
  return m + __logf(1.0f + __expf(d));
}
__device__ __forceinline__ float lae3(float a, float b, float c) {
  float m = fmaxf(fmaxf(a, b), c);
  float s = __expf(a - m) + __expf(b - m) + __expf(c - m);
  return m + __logf(s);
}

__global__ __launch_bounds__(256) void ctc_fused_kernel(
    const float* __restrict__ lp,        // (T,B,C) log-probs
    const int*   __restrict__ targets,   // (B,S)
    const int*   __restrict__ in_len,    // (B,)
    const int*   __restrict__ tgt_len,   // (B,)
    float*       __restrict__ out) {
  const int bid = blockIdx.x;

  if (bid < B_) {
    // ---------------- CTC alpha recursion: one batch row per block, wave 0 only
    if (threadIdx.x >= 64) return;
    const int lane = threadIdx.x;
    const int b = bid;
    const int* tgt = targets + b * S_;

    const int s0 = lane * 4;            // this lane owns states s0..s0+3
    const int i1 = lane * 2;            // target idx for odd state s0+1
    const int i3 = i1 + 1;              // target idx for odd state s0+3
    const int e1 = (s0 + 1 < L_) ? tgt[i1] : 0;
    const int e3 = (s0 + 3 < L_) ? tgt[i3] : 0;
    const int ep = (lane > 0 && (i1 - 1) < S_) ? tgt[i1 - 1] : 0; // ext[s0-1]
    const bool sk1 = (s0 + 1 >= 2) && (e1 != 0) && (e1 != ep);
    const bool sk3 = (e3 != 0) && (e3 != e1);   // s0+3 >= 2 always

    const int len = in_len[b];
    const int tl  = tgt_len[b];

    const size_t rowstride = (size_t)B_ * C_;
    const float* base = lp + (size_t)b * C_;    // row t: base + t*rowstride

    // t = 0 init
    float a0 = NEGF, a1 = NEGF, a2 = NEGF, a3 = NEGF;
    if (lane == 0) { a0 = base[0]; a1 = base[e1]; }

    // prefetch ring for rows t = 1..PF
    float pb[PF], p1[PF], p3[PF];
#pragma unroll
    for (int j = 0; j < PF; ++j) {
      int t = 1 + j; int tr = (t < T_) ? t : (T_ - 1);
      const float* r = base + (size_t)tr * rowstride;
      pb[j] = r[0]; p1[j] = r[e1]; p3[j] = r[e3];
    }

    constexpr int NIT = ((T_ - 1 + PF - 1) / PF) * PF;  // 1008, masked tail
    for (int t0 = 1; t0 <= NIT; t0 += PF) {
#pragma unroll
      for (int j = 0; j < PF; ++j) {
        const int t = t0 + j;
        const float lpb = pb[j], lp1v = p1[j], lp3v = p3[j];
        // issue prefetch for row t+PF (clamped; overlaps with compute below)
        {
          int tn = t + PF; int tr = (tn < T_) ? tn : (T_ - 1);
          const float* r = base + (size_t)tr * rowstride;
          pb[j] = r[0]; p1[j] = r[e1]; p3[j] = r[e3];
        }
        // neighbor state alpha[s0-1] from previous lane
        float up1 = __shfl_up(a3, 1);
        if (lane == 0) up1 = NEGF;
        // banded logsumexp update (even states never skip)
        float n0 = lae2(a0, up1);
        float n1 = lae3(a1, a0, sk1 ? up1 : NEGF);
        float n2 = lae2(a2, a1);
        float n3 = lae3(a3, a2, sk3 ? a1 : NEGF);
        const bool upd = (t < len);
        a0 = upd ? (n0 + lpb)  : a0;
        a1 = upd ? (n1 + lp1v) : a1;
        a2 = upd ? (n2 + lpb)  : a2;
        a3 = upd ? (n3 + lp3v) : a3;
      }
    }

    // final: ll = logaddexp(alpha[2*tl], alpha[2*tl-1]) via shuffles (tl is wave-uniform)
    const int last = 2 * tl;
    const int lane_hi = last >> 2,      sub_hi = last & 3;
    const int lane_lo = (last - 1) >> 2, sub_lo = (last - 1) & 3;
    float cand_hi = (sub_hi == 0) ? a0 : (sub_hi == 1) ? a1 : (sub_hi == 2) ? a2 : a3;
    float cand_lo = (sub_lo == 0) ? a0 : (sub_lo == 1) ? a1 : (sub_lo == 2) ? a2 : a3;
    float vhi = __shfl(cand_hi, lane_hi);
    float vlo = __shfl(cand_lo, lane_lo);
    if (lane == 0) {
      float ll = lae2(vhi, vlo);
      float nll = -ll;
      if (nll > 1e29f) nll = 0.0f;
      atomicAdd(out, 0.9f * nll / ((float)tl * (float)B_));
    }
  } else {
    // ---------------- entropy term: grid-stride float4 sweep of all T*B*C
    const int ebid = bid - B_;
    const size_t tid = (size_t)ebid * blockDim.x + threadIdx.x;
    const size_t nthreads = (size_t)ENT_BLOCKS * blockDim.x;
    const float4* v = (const float4*)lp;
    const size_t n4 = (size_t)T_ * B_ * C_ / 4;
    float s = 0.0f;
    for (size_t i = tid; i < n4; i += nthreads) {
      float4 x = v[i];
      s += __expf(x.x) * x.x + __expf(x.y) * x.y
         + __expf(x.z) * x.z + __expf(x.w) * x.w;
    }
    // wave reduce, one atomic per wave (no barriers needed)
    for (int o = 32; o > 0; o >>= 1) s += __shfl_down(s, o);
    if ((threadIdx.x & 63) == 0) {
      // contribution of -SMOOTHING*entropy = +0.1 * sumE / (T*B)
      atomicAdd(out, s * (0.1f / ((float)T_ * (float)B_)));
    }
  }
}

extern "C" void kernel_launch(void* const* d_in, const int* in_sizes, int n_in,
                              void* d_out, int out_size, void* d_ws, size_t ws_size,
                              hipStream_t stream) {
  const float* lp  = (const float*)d_in[0];
  const int*   tg  = (const int*)d_in[1];
  const int*   il  = (const int*)d_in[2];
  const int*   tl  = (const int*)d_in[3];
  float*       out = (float*)d_out;

  hipMemsetAsync(out, 0, sizeof(float), stream);
  dim3 grid(B_ + ENT_BLOCKS), block(256);
  ctc_fused_kernel<<<grid, block, 0, stream>>>(lp, tg, il, tl, out);
}

// Round 4
// 504.106 us; speedup vs baseline: 1.0400x; 1.0400x over previous
//
#include <hip/hip_runtime.h>

// Problem constants (fixed by the reference):
constexpr int   T_ = 1000, B_ = 64, C_ = 512, S_ = 100;
constexpr int   L_ = 2 * S_ + 1;     // 201 extended states
constexpr float NEGF = -1e30f;
constexpr int   PF = 16;             // prefetch ring depth (~16*100cy > HBM latency)
constexpr int   ENT_BLOCKS = 1984;   // entropy blocks (total grid = 64 + 1984 = 2048)
constexpr int   ROWB = B_ * C_ * 4;  // 131072 B row stride (t -> t+1)

// Force-issued global load: compiler cannot sink this to the use site.
#define GLOAD(dst, ptr) \
  asm volatile("global_load_dword %0, %1, off" : "=v"(dst) : "v"(ptr))

__device__ __forceinline__ float lae2(float a, float b) {
  float m = fmaxf(a, b);
  float d = fminf(a, b) - m;           // <= 0
  return m + __logf(1.0f + __expf(d));
}
__device__ __forceinline__ float lae3(float a, float b, float c) {
  float m = fmaxf(fmaxf(a, b), c);
  float s = __expf(a - m) + __expf(b - m) + __expf(c - m);
  return m + __logf(s);
}

__global__ __launch_bounds__(256) void ctc_fused_kernel(
    const float* __restrict__ lp,        // (T,B,C) log-probs
    const int*   __restrict__ targets,   // (B,S)
    const int*   __restrict__ in_len,    // (B,)
    const int*   __restrict__ tgt_len,   // (B,)
    float*       __restrict__ out) {
  const int bid = blockIdx.x;

  if (bid < B_) {
    // ---------------- CTC alpha recursion: one batch row per block, wave 0 only
    if (threadIdx.x >= 64) return;
    const int lane = threadIdx.x;
    const int b = bid;
    const int* tgt = targets + b * S_;

    const int s0 = lane * 4;            // this lane owns states s0..s0+3
    const int i1 = lane * 2;            // target idx for odd state s0+1
    const int i3 = i1 + 1;              // target idx for odd state s0+3
    const int e1 = (s0 + 1 < L_) ? tgt[i1] : 0;
    const int e3 = (s0 + 3 < L_) ? tgt[i3] : 0;
    const int ep = (lane > 0 && (i1 - 1) < S_) ? tgt[i1 - 1] : 0; // ext[s0-1]
    const bool sk1 = (s0 + 1 >= 2) && (e1 != 0) && (e1 != ep);
    const bool sk3 = (e3 != 0) && (e3 != e1);   // s0+3 >= 2 always

    const int len = in_len[b];
    const int tl  = tgt_len[b];

    const float* base = lp + (size_t)b * C_;    // row t: base + t*(B_*C_)

    // t = 0 init (all lanes load; select lane 0) — plain loads, completed
    // (and compiler-waited) BEFORE the asm ring starts.
    float i0 = base[0];
    float i1v = base[e1];
    float a0 = (lane == 0) ? i0  : NEGF;
    float a1 = (lane == 0) ? i1v : NEGF;
    float a2 = NEGF, a3 = NEGF;
    // Pin: force a0/a1 (and their vmcnt waits) + len/tl (lgkmcnt) to
    // materialize before the prologue, so no compiler waits land in the loop.
    asm volatile("" :: "v"(a0), "v"(a1));
    asm volatile("" :: "s"(len), "s"(tl));

    // Per-lane row pointers for the 3 gathered columns (blank, e1, e3).
    const char* pB = (const char*)(base);
    const char* p1 = (const char*)(base + e1);
    const char* p3 = (const char*)(base + e3);
    pB += ROWB; p1 += ROWB; p3 += ROWB;   // row 1

    // ---- prologue: issue rows 1..PF into the register ring (in order) ----
    float pb[PF], q1[PF], q3[PF];
#pragma unroll
    for (int j = 0; j < PF; ++j) {
      GLOAD(pb[j], (const float*)pB);
      GLOAD(q1[j], (const float*)p1);
      GLOAD(q3[j], (const float*)p3);
      pB += ROWB; p1 += ROWB; p3 += ROWB;
    }
    // pointers now at row 1+PF = 17

    constexpr int NIT = ((T_ - 1 + PF - 1) / PF) * PF;  // 1008, masked tail
    for (int t0 = 1; t0 <= NIT; t0 += PF) {
#pragma unroll
      for (int j = 0; j < PF; ++j) {
        const int t = t0 + j;
        // Wait for row t's 3 loads (issued PF steps ago): allow the
        // 3*(PF-1)=45 younger loads to stay in flight.
        asm volatile("s_waitcnt vmcnt(45)" ::: "memory");
        __builtin_amdgcn_sched_barrier(0);   // pin all consumers after the wait
        const float lpb = pb[j], lp1v = q1[j], lp3v = q3[j];

        // neighbor state alpha[s0-1] from previous lane
        float up1 = __shfl_up(a3, 1);
        if (lane == 0) up1 = NEGF;
        // banded logsumexp update (even states never skip)
        float n0 = lae2(a0, up1);
        float n1 = lae3(a1, a0, sk1 ? up1 : NEGF);
        float n2 = lae2(a2, a1);
        float n3 = lae3(a3, a2, sk3 ? a1 : NEGF);
        const bool upd = (t < len);
        a0 = upd ? (n0 + lpb)  : a0;
        a1 = upd ? (n1 + lp1v) : a1;
        a2 = upd ? (n2 + lpb)  : a2;
        a3 = upd ? (n3 + lp3v) : a3;

        // Ring slot j is now DEAD (all uses above, pinned by this fence).
        // Only now refill it — new asm def cannot interfere with the old
        // value, so no back-edge copies of in-flight registers can arise.
        __builtin_amdgcn_sched_barrier(0);
        GLOAD(pb[j], (const float*)pB);
        GLOAD(q1[j], (const float*)p1);
        GLOAD(q3[j], (const float*)p3);
        // advance to next row, clamped at the last row (t=999)
        const int adv = (t + PF < T_ - 1) ? ROWB : 0;
        pB += adv; p1 += adv; p3 += adv;
      }
    }
    // Drain outstanding ring loads before wave exit.
    asm volatile("s_waitcnt vmcnt(0)" ::: "memory");

    // final: ll = logaddexp(alpha[2*tl], alpha[2*tl-1]) via shuffles (tl is wave-uniform)
    const int last = 2 * tl;
    const int lane_hi = last >> 2,       sub_hi = last & 3;
    const int lane_lo = (last - 1) >> 2, sub_lo = (last - 1) & 3;
    float cand_hi = (sub_hi == 0) ? a0 : (sub_hi == 1) ? a1 : (sub_hi == 2) ? a2 : a3;
    float cand_lo = (sub_lo == 0) ? a0 : (sub_lo == 1) ? a1 : (sub_lo == 2) ? a2 : a3;
    float vhi = __shfl(cand_hi, lane_hi);
    float vlo = __shfl(cand_lo, lane_lo);
    if (lane == 0) {
      float ll = lae2(vhi, vlo);
      float nll = -ll;
      if (nll > 1e29f) nll = 0.0f;
      atomicAdd(out, 0.9f * nll / ((float)tl * (float)B_));
    }
  } else {
    // ---------------- entropy term: grid-stride float4 sweep of all T*B*C
    const int ebid = bid - B_;
    const size_t tid = (size_t)ebid * blockDim.x + threadIdx.x;
    const size_t nthreads = (size_t)ENT_BLOCKS * blockDim.x;
    const float4* v = (const float4*)lp;
    const size_t n4 = (size_t)T_ * B_ * C_ / 4;
    float s = 0.0f;
    for (size_t i = tid; i < n4; i += nthreads) {
      float4 x = v[i];
      s += __expf(x.x) * x.x + __expf(x.y) * x.y
         + __expf(x.z) * x.z + __expf(x.w) * x.w;
    }
    // wave reduce, one atomic per wave (no barriers needed)
    for (int o = 32; o > 0; o >>= 1) s += __shfl_down(s, o);
    if ((threadIdx.x & 63) == 0) {
      // contribution of -SMOOTHING*entropy = +0.1 * sumE / (T*B)
      atomicAdd(out, s * (0.1f / ((float)T_ * (float)B_)));
    }
  }
}

extern "C" void kernel_launch(void* const* d_in, const int* in_sizes, int n_in,
                              void* d_out, int out_size, void* d_ws, size_t ws_size,
                              hipStream_t stream) {
  const float* lp  = (const float*)d_in[0];
  const int*   tg  = (const int*)d_in[1];
  const int*   il  = (const int*)d_in[2];
  const int*   tl  = (const int*)d_in[3];
  float*       out = (float*)d_out;

  hipMemsetAsync(out, 0, sizeof(float), stream);
  dim3 grid(B_ + ENT_BLOCKS), block(256);
  ctc_fused_kernel<<<grid, block, 0, stream>>>(lp, tg, il, tl, out);
}

// Round 6
// 322.325 us; speedup vs baseline: 1.6266x; 1.5640x over previous
//
#include <hip/hip_runtime.h>

// Problem constants (fixed by the reference):
constexpr int   T_ = 1000, B_ = 64, C_ = 512, S_ = 100;
constexpr int   L_ = 2 * S_ + 1;       // 201 extended states
constexpr float NEGF = -1e30f;
constexpr int   PF = 21;               // ring depth: 21 steps * ~50cy > HBM latency
constexpr int   ENT_BLOCKS = 1984;     // entropy blocks (grid = 64 + 1984 = 2048)
constexpr int   ROWB = B_ * C_ * 4;    // 131072 B row stride (t -> t+1)
constexpr int   ENT_W = ENT_BLOCKS * 4;          // 7936 entropy wave slots
constexpr int   WS_N  = ENT_W + B_;              // + 64 CTC slots
constexpr float K2    = 1.44269504088896340736f; // log2(e)
constexpr float LN2   = 0.69314718055994530942f;

// saddr-form forced load: uniform SGPR base + 32-bit per-lane offset.
// "+v" ties dst in/out -> same physreg across refills (no back-edge copies).
#define GLOADI(dst, voff, sbase) \
  asm volatile("global_load_dword %0, %1, %2" : "+v"(dst) : "v"(voff), "s"(sbase))

// raw v_exp_f32 (2^x). HIP has no __exp2f device intrinsic (round-5 lesson).
__device__ __forceinline__ float fexp2(float x) {
#if __has_builtin(__builtin_amdgcn_exp2f)
  return __builtin_amdgcn_exp2f(x);
#else
  float r; asm("v_exp_f32 %0, %1" : "=v"(r) : "v"(x)); return r;
#endif
}

// base-2 log-add-exp
__device__ __forceinline__ float l2ae2(float a, float b) {
  float m = fmaxf(a, b);
  return m + __log2f(fexp2(a - m) + fexp2(b - m));
}
__device__ __forceinline__ float l2ae3(float a, float b, float c) {
  float m = fmaxf(fmaxf(a, b), c);
  return m + __log2f(fexp2(a - m) + fexp2(b - m) + fexp2(c - m));
}

#define RING(X) X(0) X(1) X(2) X(3) X(4) X(5) X(6) X(7) X(8) X(9) X(10) \
                X(11) X(12) X(13) X(14) X(15) X(16) X(17) X(18) X(19) X(20)

__global__ __launch_bounds__(256, 2) void ctc_fused_kernel(
    const float* __restrict__ lp,        // (T,B,C) log-probs
    const int*   __restrict__ targets,   // (B,S)
    const int*   __restrict__ in_len,    // (B,)
    const int*   __restrict__ tgt_len,   // (B,)
    float*       __restrict__ ws) {      // WS_N partial slots
  const int bid = blockIdx.x;

  if (bid < B_) {
    // ---------------- CTC alpha recursion: one batch row per block, wave 0 only
    if (threadIdx.x >= 64) return;
    const int lane = threadIdx.x;
    const int b = bid;
    const int* tgt = targets + b * S_;

    const int s0 = lane * 4;            // this lane owns states s0..s0+3
    const int i1 = lane * 2;            // target idx for odd state s0+1
    const int e1 = (s0 + 1 < L_) ? tgt[i1] : 0;
    const int e3 = (s0 + 3 < L_) ? tgt[i1 + 1] : 0;
    const int ep = (lane > 0 && (i1 - 1) < S_) ? tgt[i1 - 1] : 0; // ext[s0-1]
    const bool sk1 = (s0 + 1 >= 2) && (e1 != 0) && (e1 != ep);
    const bool sk3 = (e3 != 0) && (e3 != e1);   // s0+3 >= 2 always

    const int len = in_len[b];
    const int tl  = tgt_len[b];

    const float* base = lp + (size_t)b * C_;    // row t: base + t*(B_*C_)

    // t = 0 init (base-2 domain). Plain loads, pinned to complete pre-loop.
    float i0  = base[0];
    float i1v = base[e1];
    float a0 = (lane == 0) ? i0 * K2  : NEGF;
    float a1 = (lane == 0) ? i1v * K2 : NEGF;
    float a2 = NEGF, a3 = NEGF;
    asm volatile("" :: "v"(a0), "v"(a1));
    asm volatile("" :: "s"(len), "s"(tl));

    // 32-bit offsets for the 3 gathered columns (blank, e1, e3), row 1.
    unsigned voffB = (unsigned)ROWB;
    unsigned voff1 = (unsigned)(ROWB + e1 * 4);
    unsigned voff3 = (unsigned)(ROWB + e3 * 4);

    // Named-scalar ring (guaranteed registers; no arrays, no indexing).
#define DECLR(J) float pb##J = 0.f, q1##J = 0.f, q3##J = 0.f;
    RING(DECLR)
#undef DECLR

    __builtin_amdgcn_s_setprio(1);

    // ---- prologue: issue rows 1..21 (in order) ----
#define ISSUER(J) \
    GLOADI(pb##J, voffB, base); \
    GLOADI(q1##J, voff1, base); \
    GLOADI(q3##J, voff3, base); \
    voffB += ROWB; voff1 += ROWB; voff3 += ROWB;
    RING(ISSUER)
#undef ISSUER
    // offsets now at row 1+PF = 22

    // ---- main loop: 48 chunks x 21 phases = 1008 masked steps ----
#define STEPR(J) { \
    const int t = t0 + J; \
    asm volatile("s_waitcnt vmcnt(60)" ::: "memory"); \
    __builtin_amdgcn_sched_barrier(0); \
    const float lpb  = pb##J * K2; \
    const float lp1v = q1##J * K2; \
    const float lp3v = q3##J * K2; \
    float up1 = __shfl_up(a3, 1); \
    if (lane == 0) up1 = NEGF; \
    float n0 = l2ae2(a0, up1); \
    float n1 = l2ae3(a1, a0, sk1 ? up1 : NEGF); \
    float n2 = l2ae2(a2, a1); \
    float n3 = l2ae3(a3, a2, sk3 ? a1 : NEGF); \
    const bool upd = (t < len); \
    a0 = upd ? (n0 + lpb)  : a0; \
    a1 = upd ? (n1 + lp1v) : a1; \
    a2 = upd ? (n2 + lpb)  : a2; \
    a3 = upd ? (n3 + lp3v) : a3; \
    __builtin_amdgcn_sched_barrier(0); \
    GLOADI(pb##J, voffB, base); \
    GLOADI(q1##J, voff1, base); \
    GLOADI(q3##J, voff3, base); \
    const unsigned adv = (t + PF < T_ - 1) ? (unsigned)ROWB : 0u; \
    voffB += adv; voff1 += adv; voff3 += adv; \
  }
    for (int t0 = 1; t0 <= 1 + 47 * PF; t0 += PF) {
      RING(STEPR)
    }
#undef STEPR
    // Drain outstanding ring loads before wave exit.
    asm volatile("s_waitcnt vmcnt(0)" ::: "memory");
    __builtin_amdgcn_s_setprio(0);

    // final: ll = ln2 * l2ae2(ahat[2*tl], ahat[2*tl-1]) via shuffles (tl uniform)
    const int last = 2 * tl;
    const int lane_hi = last >> 2,       sub_hi = last & 3;
    const int lane_lo = (last - 1) >> 2, sub_lo = (last - 1) & 3;
    float cand_hi = (sub_hi == 0) ? a0 : (sub_hi == 1) ? a1 : (sub_hi == 2) ? a2 : a3;
    float cand_lo = (sub_lo == 0) ? a0 : (sub_lo == 1) ? a1 : (sub_lo == 2) ? a2 : a3;
    float vhi = __shfl(cand_hi, lane_hi);
    float vlo = __shfl(cand_lo, lane_lo);
    if (lane == 0) {
      float ll = LN2 * l2ae2(vhi, vlo);
      float nll = -ll;
      if (nll > 1e29f) nll = 0.0f;
      ws[ENT_W + b] = 0.9f * nll / ((float)tl * (float)B_);
    }
  } else {
    // ---------------- entropy term: grid-stride float4 sweep of all T*B*C
    const int ebid = bid - B_;
    const size_t tid = (size_t)ebid * blockDim.x + threadIdx.x;
    const size_t nthreads = (size_t)ENT_BLOCKS * blockDim.x;
    const float4* v = (const float4*)lp;
    const size_t n4 = (size_t)T_ * B_ * C_ / 4;
    float s = 0.0f;
    for (size_t i = tid; i < n4; i += nthreads) {
      float4 x = v[i];
      s += __expf(x.x) * x.x + __expf(x.y) * x.y
         + __expf(x.z) * x.z + __expf(x.w) * x.w;
    }
    // wave reduce, one plain store per wave (no atomics)
    for (int o = 32; o > 0; o >>= 1) s += __shfl_down(s, o);
    if ((threadIdx.x & 63) == 0) {
      const int wslot = ebid * 4 + (int)(threadIdx.x >> 6);
      ws[wslot] = s;   // raw partial of sum(exp(lp)*lp)
    }
  }
}

__global__ __launch_bounds__(256) void finalize_kernel(
    const float* __restrict__ ws, float* __restrict__ out) {
  const float entScale = 0.1f / ((float)T_ * (float)B_);
  float acc = 0.0f;
  for (int i = threadIdx.x; i < WS_N; i += 256) {
    float v = ws[i];
    acc += (i < ENT_W) ? v * entScale : v;
  }
  // block reduce: wave shuffle + LDS across 4 waves
  for (int o = 32; o > 0; o >>= 1) acc += __shfl_down(acc, o);
  __shared__ float red[4];
  if ((threadIdx.x & 63) == 0) red[threadIdx.x >> 6] = acc;
  __syncthreads();
  if (threadIdx.x == 0) out[0] = red[0] + red[1] + red[2] + red[3];
}

extern "C" void kernel_launch(void* const* d_in, const int* in_sizes, int n_in,
                              void* d_out, int out_size, void* d_ws, size_t ws_size,
                              hipStream_t stream) {
  const float* lp  = (const float*)d_in[0];
  const int*   tg  = (const int*)d_in[1];
  const int*   il  = (const int*)d_in[2];
  const int*   tl  = (const int*)d_in[3];
  float*       ws  = (float*)d_ws;
  float*       out = (float*)d_out;

  dim3 grid(B_ + ENT_BLOCKS), block(256);
  ctc_fused_kernel<<<grid, block, 0, stream>>>(lp, tg, il, tl, ws);
  finalize_kernel<<<1, 256, 0, stream>>>(ws, out);
}